// Round 8
// baseline (29.048 us; speedup 1.0000x reference)
//
#include <hip/hip_runtime.h>
#include <math.h>

#define NB 2
#define NN 512
#define DD 128
#define LOG2E 1.4426950408889634f

typedef unsigned long long ull;

__device__ __forceinline__ float exp2_hw(float x) {
    float r; asm("v_exp_f32 %0, %1" : "=v"(r) : "v"(x)); return r;
}
__device__ __forceinline__ float silu_f(float x) {
    float e = exp2_hw(-LOG2E * x);
    return x * __builtin_amdgcn_rcpf(1.0f + e);
}

// acc += pre * W.w * sigmoid ; pre = bb + f1*W.x + f2*W.y + f3*W.z  (all -log2e scaled)
#define UPD(Wq, bbv, s)                                                        \
    { float pre = fmaf(f3[s], Wq.z, fmaf(f2[s], Wq.y, fmaf(f1[s], Wq.x, bbv))); \
      float e   = exp2_hw(pre);                                                \
      float rc  = __builtin_amdgcn_rcpf(1.0f + e);                             \
      acc[s]    = fmaf(pre * Wq.w, rc, acc[s]); }

// ---------------------------------------------------------------------------
// One kernel, 512 blocks x 256 threads; each block owns TWO adjacent rows.
// One weight load feeds 6 FMAs (2 rows x 3 mats) in phase A -> L2 weight
// traffic halves vs R7. Pass-1: 4 slots/thread (2 rows x 2 rounds); 6 LDS
// b128 reads per t4 serve >=8 elements. Deterministic compaction, no atomics.
// ---------------------------------------------------------------------------
__global__ __launch_bounds__(256) void k_all(
    const float* __restrict__ nf,
    const float* __restrict__ coords,
    const int*   __restrict__ mask,
    const float* __restrict__ Ws1, const float* __restrict__ bs1,
    const float* __restrict__ Ws2, const float* __restrict__ bs2,
    const float* __restrict__ Wv1, const float* __restrict__ bv1,
    const float* __restrict__ Wv2, const float* __restrict__ bv2,
    const float* __restrict__ Wa1, const float* __restrict__ ba1,
    const float* __restrict__ Wa2, const float* __restrict__ ba2p,
    float* __restrict__ scalar_out,
    float* __restrict__ vec_out)
{
    __shared__ __align__(16) float  s_nf[2][DD];
    __shared__ __align__(16) float  s_hs[2][DD];
    __shared__ __align__(16) float  s_hv[2][DD];
    __shared__ __align__(16) float  s_bb[2][DD];   // -l2e*base per row
    __shared__ __align__(16) float4 s_w4[DD];      // (-l2e*w0,-l2e*w1,-l2e*w2,-Wa2)
    __shared__ float  s_part[3][2][256];
    __shared__ short  s_act[2][NN];
    __shared__ int    s_cnt8[2][8], s_off8[2][8], s_nact[2];
    __shared__ float  s_red[2][4], s_red2[2][4][4];

    const int row0 = blockIdx.x * 2;
    const int b    = row0 >> 9;
    const int tid  = threadIdx.x;
    const int lane = tid & 63;
    const int wid  = tid >> 6;
    const int c    = tid & 127;
    const int h    = tid >> 7;

    { const int rr = tid >> 7, t = tid & 127;
      s_nf[rr][t] = nf[(row0 + rr) * DD + t]; }

    // ---- mask ballots for both rows ----
    const int* mrow0 = mask + (size_t)row0 * NN;
    const int* mrow1 = mrow0 + NN;
    const bool m00 = (mrow0[tid] != 0), m01 = (mrow0[tid + 256] != 0);
    const bool m10 = (mrow1[tid] != 0), m11 = (mrow1[tid + 256] != 0);
    const ull  b00 = __ballot(m00), b01 = __ballot(m01);
    const ull  b10 = __ballot(m10), b11 = __ballot(m11);
    if (lane == 0) {
        s_cnt8[0][wid]     = __popcll(b00);
        s_cnt8[0][4 + wid] = __popcll(b01);
        s_cnt8[1][wid]     = __popcll(b10);
        s_cnt8[1][4 + wid] = __popcll(b11);
    }
    __syncthreads();   // s_nf + counts ready

    if (tid < 2) {
        int a = 0;
        #pragma unroll
        for (int q = 0; q < 8; ++q) { s_off8[tid][q] = a; a += s_cnt8[tid][q]; }
        s_nact[tid] = a;
    }

    // ---- phase A: layer-1 GEMVs, 2 rows x 3 mats per weight load ----
    {
        float pS0 = 0.f, pS1 = 0.f, pV0 = 0.f, pV1 = 0.f, pA0 = 0.f, pA1 = 0.f;
        const float4* nfq0 = (const float4*)s_nf[0];
        const float4* nfq1 = (const float4*)s_nf[1];
        const int kq0 = h * 16;
        #pragma unroll 4
        for (int kk = 0; kk < 16; ++kk) {
            float4 x0 = nfq0[kq0 + kk];
            float4 x1 = nfq1[kq0 + kk];
            const int k = (kq0 + kk) * 4;
            float w;
            w = Ws1[(k+0)*DD + c]; pS0 = fmaf(x0.x, w, pS0); pS1 = fmaf(x1.x, w, pS1);
            w = Ws1[(k+1)*DD + c]; pS0 = fmaf(x0.y, w, pS0); pS1 = fmaf(x1.y, w, pS1);
            w = Ws1[(k+2)*DD + c]; pS0 = fmaf(x0.z, w, pS0); pS1 = fmaf(x1.z, w, pS1);
            w = Ws1[(k+3)*DD + c]; pS0 = fmaf(x0.w, w, pS0); pS1 = fmaf(x1.w, w, pS1);
            w = Wv1[(k+0)*DD + c]; pV0 = fmaf(x0.x, w, pV0); pV1 = fmaf(x1.x, w, pV1);
            w = Wv1[(k+1)*DD + c]; pV0 = fmaf(x0.y, w, pV0); pV1 = fmaf(x1.y, w, pV1);
            w = Wv1[(k+2)*DD + c]; pV0 = fmaf(x0.z, w, pV0); pV1 = fmaf(x1.z, w, pV1);
            w = Wv1[(k+3)*DD + c]; pV0 = fmaf(x0.w, w, pV0); pV1 = fmaf(x1.w, w, pV1);
            w = Wa1[(k+0)*DD + c]; pA0 = fmaf(x0.x, w, pA0); pA1 = fmaf(x1.x, w, pA1);
            w = Wa1[(k+1)*DD + c]; pA0 = fmaf(x0.y, w, pA0); pA1 = fmaf(x1.y, w, pA1);
            w = Wa1[(k+2)*DD + c]; pA0 = fmaf(x0.z, w, pA0); pA1 = fmaf(x1.z, w, pA1);
            w = Wa1[(k+3)*DD + c]; pA0 = fmaf(x0.w, w, pA0); pA1 = fmaf(x1.w, w, pA1);
        }
        s_part[0][0][tid] = pS0; s_part[0][1][tid] = pS1;
        s_part[1][0][tid] = pV0; s_part[1][1][tid] = pV1;
        s_part[2][0][tid] = pA0; s_part[2][1][tid] = pA1;
    }
    __syncthreads();   // partials + s_off8 ready

    // ---- activations / base / weight-quads / compacted indices ----
    {
        const int rr = tid >> 7, t = tid & 127;
        s_hs[rr][t] = silu_f(s_part[0][rr][t] + s_part[0][rr][128 + t] + bs1[t]);
        s_hv[rr][t] = silu_f(s_part[1][rr][t] + s_part[1][rr][128 + t] + bv1[t]);
        s_bb[rr][t] = -LOG2E * (s_part[2][rr][t] + s_part[2][rr][128 + t] + ba1[t]);
    }
    if (tid < DD) {
        float4 w;
        w.x = -LOG2E * Wa1[128 * DD + tid];
        w.y = -LOG2E * Wa1[129 * DD + tid];
        w.z = -LOG2E * Wa1[130 * DD + tid];
        w.w = -Wa2[tid];
        s_w4[tid] = w;
    }
    {
        const ull lm = (1ull << lane) - 1ull;
        if (m00) s_act[0][s_off8[0][wid]     + __popcll(b00 & lm)] = (short)tid;
        if (m01) s_act[0][s_off8[0][4 + wid] + __popcll(b01 & lm)] = (short)(tid + 256);
        if (m10) s_act[1][s_off8[1][wid]     + __popcll(b10 & lm)] = (short)tid;
        if (m11) s_act[1][s_off8[1][4 + wid] + __popcll(b11 & lm)] = (short)(tid + 256);
    }
    __syncthreads();   // s_hs/s_hv/s_bb/s_w4/s_act ready; s_part free

    // ---- phase B: Ws2 GEMV (2 rows) + vf3 partials (both rows) ----
    {
        float p0 = 0.f, p1 = 0.f;
        const float4* h0 = (const float4*)s_hs[0];
        const float4* h1 = (const float4*)s_hs[1];
        const int kq0 = h * 16;
        #pragma unroll 4
        for (int kk = 0; kk < 16; ++kk) {
            float4 x0 = h0[kq0 + kk];
            float4 x1 = h1[kq0 + kk];
            const int k = (kq0 + kk) * 4;
            float w;
            w = Ws2[(k+0)*DD + c]; p0 = fmaf(x0.x, w, p0); p1 = fmaf(x1.x, w, p1);
            w = Ws2[(k+1)*DD + c]; p0 = fmaf(x0.y, w, p0); p1 = fmaf(x1.y, w, p1);
            w = Ws2[(k+2)*DD + c]; p0 = fmaf(x0.z, w, p0); p1 = fmaf(x1.z, w, p1);
            w = Ws2[(k+3)*DD + c]; p0 = fmaf(x0.w, w, p0); p1 = fmaf(x1.w, w, p1);
        }
        s_part[0][0][tid] = p0; s_part[0][1][tid] = p1;
    }
    float* vfp = &s_part[1][0][0];          // 192 floats, s_part free region
    if (tid < 192) {
        const int rr  = tid / 96;
        const int rem = tid % 96;
        const int col = rem >> 5;           // 0..2
        const int kq  = rem & 31;           // k = 4kq..4kq+3
        float vp = 0.f;
        #pragma unroll
        for (int u = 0; u < 4; ++u) {
            const int k = 4 * kq + u;
            vp = fmaf(s_hv[rr][k], Wv2[k * DD + col], vp);
        }
        vfp[tid] = vp;
    }

    // ---- attention pass 1 (no dependence on s_part) ----
    const int n0 = __builtin_amdgcn_readfirstlane(s_nact[0]);
    const int n1 = __builtin_amdgcn_readfirstlane(s_nact[1]);
    const int wb = (tid & ~63) + 256;
    const bool has1r0 = wb < n0;            // wave-uniform
    const bool has1r1 = wb < n1;
    bool act[4];
    act[0] = tid < n0;  act[1] = tid + 256 < n0;
    act[2] = tid < n1;  act[3] = tid + 256 < n1;

    const float ba2l = ba2p[0] * LOG2E;
    float xi[2][3];
    #pragma unroll
    for (int rr = 0; rr < 2; ++rr)
        #pragma unroll
        for (int cc = 0; cc < 3; ++cc) xi[rr][cc] = coords[(row0 + rr) * 3 + cc];
    const float* cb = coords + (size_t)b * NN * 3;

    float dx[4], dy[4], dz[4], f1[4], f2[4], f3[4], acc[4];
    #pragma unroll
    for (int s = 0; s < 4; ++s) {
        acc[s] = ba2l;
        dx[s] = dy[s] = dz[s] = f1[s] = f2[s] = f3[s] = 0.f;
    }
    #pragma unroll
    for (int s = 0; s < 4; ++s) {
        const int rr = s >> 1;
        const bool rnd1 = (s & 1);
        if (rnd1 && !(rr == 0 ? has1r0 : has1r1)) continue;
        const int a = tid + (rnd1 ? 256 : 0);
        const int j = ((int)s_act[rr][act[s] ? a : 0]) & (NN - 1);
        dx[s] = xi[rr][0] - cb[j * 3 + 0];
        dy[s] = xi[rr][1] - cb[j * 3 + 1];
        dz[s] = xi[rr][2] - cb[j * 3 + 2];
        float d2 = fmaf(dx[s], dx[s], fmaf(dy[s], dy[s], dz[s] * dz[s]));
        float d  = sqrtf(d2);
        f1[s] = d;
        float x  = d + 1e-6f;
        float rc = __builtin_amdgcn_rcpf(x);
        f2[s] = rc * fmaf(-x, rc, 2.0f);    // Newton: 1/(d+1e-6)
        f3[s] = exp2_hw(-LOG2E * d);        // exp(-d)
    }

    const float4* bbq0 = (const float4*)s_bb[0];
    const float4* bbq1 = (const float4*)s_bb[1];
    for (int t4 = 0; t4 < DD / 4; ++t4) {
        float4 W0 = s_w4[4 * t4 + 0];
        float4 W1 = s_w4[4 * t4 + 1];
        float4 W2 = s_w4[4 * t4 + 2];
        float4 W3 = s_w4[4 * t4 + 3];
        float4 bA = bbq0[t4];
        float4 bB = bbq1[t4];
        UPD(W0, bA.x, 0); UPD(W1, bA.y, 0); UPD(W2, bA.z, 0); UPD(W3, bA.w, 0);
        UPD(W0, bB.x, 2); UPD(W1, bB.y, 2); UPD(W2, bB.z, 2); UPD(W3, bB.w, 2);
        if (has1r0) {
            UPD(W0, bA.x, 1); UPD(W1, bA.y, 1); UPD(W2, bA.z, 1); UPD(W3, bA.w, 1);
        }
        if (has1r1) {
            UPD(W0, bB.x, 3); UPD(W1, bB.y, 3); UPD(W2, bB.z, 3); UPD(W3, bB.w, 3);
        }
    }
    __syncthreads();   // phase-B s_part + vfp ready

    // ---- scalar output: 2 rows in parallel by thread halves ----
    {
        const int rr = tid >> 7, t = tid & 127;
        scalar_out[(row0 + rr) * DD + t] =
            s_part[0][rr][t] + s_part[0][rr][128 + t] + bs2[t];
    }

    // ---- block max per row ----
    float mloc[2] = { -__builtin_inff(), -__builtin_inff() };
    if (act[0]) mloc[0] = acc[0];
    if (has1r0 && act[1]) mloc[0] = fmaxf(mloc[0], acc[1]);
    if (act[2]) mloc[1] = acc[2];
    if (has1r1 && act[3]) mloc[1] = fmaxf(mloc[1], acc[3]);
    #pragma unroll
    for (int ofs = 32; ofs >= 1; ofs >>= 1) {
        mloc[0] = fmaxf(mloc[0], __shfl_xor(mloc[0], ofs));
        mloc[1] = fmaxf(mloc[1], __shfl_xor(mloc[1], ofs));
    }
    if (lane == 0) { s_red[0][wid] = mloc[0]; s_red[1][wid] = mloc[1]; }
    __syncthreads();
    const float mx0 = fmaxf(fmaxf(s_red[0][0], s_red[0][1]), fmaxf(s_red[0][2], s_red[0][3]));
    const float mx1 = fmaxf(fmaxf(s_red[1][0], s_red[1][1]), fmaxf(s_red[1][2], s_red[1][3]));

    // ---- pass 2: exp + weighted diff per row ----
    float es[2] = {0.f, 0.f}, wx[2] = {0.f, 0.f}, wy[2] = {0.f, 0.f}, wz[2] = {0.f, 0.f};
    if (act[0]) {
        float e = exp2_hw(acc[0] - mx0);
        es[0] += e; wx[0] = fmaf(e, dx[0], wx[0]); wy[0] = fmaf(e, dy[0], wy[0]); wz[0] = fmaf(e, dz[0], wz[0]);
    }
    if (has1r0 && act[1]) {
        float e = exp2_hw(acc[1] - mx0);
        es[0] += e; wx[0] = fmaf(e, dx[1], wx[0]); wy[0] = fmaf(e, dy[1], wy[0]); wz[0] = fmaf(e, dz[1], wz[0]);
    }
    if (act[2]) {
        float e = exp2_hw(acc[2] - mx1);
        es[1] += e; wx[1] = fmaf(e, dx[2], wx[1]); wy[1] = fmaf(e, dy[2], wy[1]); wz[1] = fmaf(e, dz[2], wz[1]);
    }
    if (has1r1 && act[3]) {
        float e = exp2_hw(acc[3] - mx1);
        es[1] += e; wx[1] = fmaf(e, dx[3], wx[1]); wy[1] = fmaf(e, dy[3], wy[1]); wz[1] = fmaf(e, dz[3], wz[1]);
    }
    #pragma unroll
    for (int ofs = 32; ofs >= 1; ofs >>= 1) {
        #pragma unroll
        for (int rr = 0; rr < 2; ++rr) {
            es[rr] += __shfl_xor(es[rr], ofs);
            wx[rr] += __shfl_xor(wx[rr], ofs);
            wy[rr] += __shfl_xor(wy[rr], ofs);
            wz[rr] += __shfl_xor(wz[rr], ofs);
        }
    }
    if (lane == 0) {
        #pragma unroll
        for (int rr = 0; rr < 2; ++rr) {
            s_red2[rr][wid][0] = es[rr]; s_red2[rr][wid][1] = wx[rr];
            s_red2[rr][wid][2] = wy[rr]; s_red2[rr][wid][3] = wz[rr];
        }
    }
    __syncthreads();

    if (tid < 6) {
        const int rr = tid / 3, cc = tid % 3;
        float tot = s_red2[rr][0][0] + s_red2[rr][1][0] + s_red2[rr][2][0] + s_red2[rr][3][0];
        float num = s_red2[rr][0][1+cc] + s_red2[rr][1][1+cc] + s_red2[rr][2][1+cc] + s_red2[rr][3][1+cc];
        float vf = bv2[cc];
        const float* pp = &vfp[rr * 96 + cc * 32];
        #pragma unroll 8
        for (int q = 0; q < 32; ++q) vf += pp[q];
        vec_out[(row0 + rr) * 3 + cc] = (num / tot) * vf;
    }
}

extern "C" void kernel_launch(void* const* d_in, const int* in_sizes, int n_in,
                              void* d_out, int out_size, void* d_ws, size_t ws_size,
                              hipStream_t stream) {
    const float* nf     = (const float*)d_in[0];
    const float* coords = (const float*)d_in[1];
    const int*   mask   = (const int*)  d_in[2];
    const float* Ws1 = (const float*)d_in[3];  const float* bs1 = (const float*)d_in[4];
    const float* Ws2 = (const float*)d_in[5];  const float* bs2 = (const float*)d_in[6];
    const float* Wv1 = (const float*)d_in[7];  const float* bv1 = (const float*)d_in[8];
    const float* Wv2 = (const float*)d_in[9];  const float* bv2 = (const float*)d_in[10];
    const float* Wa1 = (const float*)d_in[11]; const float* ba1 = (const float*)d_in[12];
    const float* Wa2 = (const float*)d_in[13]; const float* ba2 = (const float*)d_in[14];

    float* scalar_out = (float*)d_out;                   // [NB*NN*DD]
    float* vec_out    = (float*)d_out + NB * NN * DD;    // [NB*NN*3]

    hipLaunchKernelGGL(k_all, dim3(NB * NN / 2), dim3(256), 0, stream,
                       nf, coords, mask,
                       Ws1, bs1, Ws2, bs2, Wv1, bv1, Wv2, bv2,
                       Wa1, ba1, Wa2, ba2,
                       scalar_out, vec_out);
}

// Round 9
// 26.613 us; speedup vs baseline: 1.0915x; 1.0915x over previous
//
#include <hip/hip_runtime.h>
#include <math.h>

#define NB 2
#define NN 512
#define DD 128
#define LOG2E 1.4426950408889634f

typedef unsigned long long ull;

__device__ __forceinline__ float exp2_hw(float x) {
    float r; asm("v_exp_f32 %0, %1" : "=v"(r) : "v"(x)); return r;
}
__device__ __forceinline__ float silu_f(float x) {
    float e = exp2_hw(-LOG2E * x);
    return x * __builtin_amdgcn_rcpf(1.0f + e);
}

// One UPD for t-value with weight quad Wq component pairing:
// pre = bb + f1*Wq.x + f2*Wq.y + f3*Wq.z (log2-scaled), acc += pre*Wq.w*sigmoid
#define UPD1(Wq, BBC, F1, F2, F3, ACC)                                         \
    { float pre = fmaf(F3, Wq.z, fmaf(F2, Wq.y, fmaf(F1, Wq.x, BBC)));         \
      float e   = exp2_hw(pre);                                                \
      float rc  = __builtin_amdgcn_rcpf(1.0f + e);                             \
      ACC = fmaf(pre * Wq.w, rc, ACC); }

#define UPD4(BB, F1, F2, F3, ACC)                                              \
    UPD1(W0, BB.x, F1, F2, F3, ACC) UPD1(W1, BB.y, F1, F2, F3, ACC)            \
    UPD1(W2, BB.z, F1, F2, F3, ACC) UPD1(W3, BB.w, F1, F2, F3, ACC)

// compute f1,f2,f3 for compacted slot a of row rr (n = nact[rr])
#define SETUP(rr, A, NACT, F1, F2, F3)                                         \
    { int a_ = (A);                                                            \
      int j_ = ((int)s_act[rr][(a_ < (NACT)) ? a_ : 0]) & (NN - 1);            \
      float dx_ = xiv[rr][0] - cb[j_ * 3 + 0];                                 \
      float dy_ = xiv[rr][1] - cb[j_ * 3 + 1];                                 \
      float dz_ = xiv[rr][2] - cb[j_ * 3 + 2];                                 \
      float d_  = sqrtf(fmaf(dx_, dx_, fmaf(dy_, dy_, dz_ * dz_)));            \
      F1 = d_;                                                                 \
      float x_  = d_ + 1e-6f;                                                  \
      float rc_ = __builtin_amdgcn_rcpf(x_);                                   \
      F2 = rc_ * fmaf(-x_, rc_, 2.0f);                                         \
      F3 = exp2_hw(-LOG2E * d_); }

// ---------------------------------------------------------------------------
// 512 blocks x 512 threads, 2 rows per block (16 waves/CU = 4/SIMD).
// Pass-1 factorization: q4 = tid>>7 owns t4 in [q4*8, q4*8+8); u = tid&127;
// 8 slots/thread (2 rows x 4 rounds, rounds wave-uniformly guarded).
// Per wave per t4: 6 broadcast ds_read_b128 serve 16 UPDs (was 5 per 4).
// Partial logits combine via s_lg[row][q4][a]; bias added at combine.
// Deterministic compaction (ballot+scan, no atomics).
// ---------------------------------------------------------------------------
__global__ __launch_bounds__(512) void k_all(
    const float* __restrict__ nf,
    const float* __restrict__ coords,
    const int*   __restrict__ mask,
    const float* __restrict__ Ws1, const float* __restrict__ bs1,
    const float* __restrict__ Ws2, const float* __restrict__ bs2,
    const float* __restrict__ Wv1, const float* __restrict__ bv1,
    const float* __restrict__ Wv2, const float* __restrict__ bv2,
    const float* __restrict__ Wa1, const float* __restrict__ ba1,
    const float* __restrict__ Wa2, const float* __restrict__ ba2p,
    float* __restrict__ scalar_out,
    float* __restrict__ vec_out)
{
    __shared__ __align__(16) float  s_nf[2][DD];
    __shared__ __align__(16) float  s_hs[2][DD];
    __shared__ __align__(16) float  s_hv[2][DD];
    __shared__ __align__(16) float  s_bb[2][DD];     // -l2e*base per row
    __shared__ __align__(16) float4 s_w4[DD];        // (-l2e*w0,-l2e*w1,-l2e*w2,-Wa2)
    __shared__ float  s_part[3][2][4][DD];           // [mat][row][kquarter][col]
    __shared__ float  s_lg[2][4][NN];                // [row][q4][a] partial logits
    __shared__ short  s_act[2][NN];
    __shared__ float  s_vp[192];
    __shared__ int    s_cnt[2][8], s_off[2][8], s_nact[2];
    __shared__ float  s_red[2][4], s_red2[2][4][4];

    const int row0 = blockIdx.x * 2;
    const int b    = row0 >> 9;
    const int tid  = threadIdx.x;
    const int lane = tid & 63;
    const int wid  = tid >> 6;           // 0..7
    const int c    = tid & 127;
    const int h    = tid >> 7;           // 0..3 (k-quarter / t4-quarter)
    const int u    = tid & 127;
    const int ub   = tid & 64;           // wave-uniform u base

    // ---- S0: load nf + mask ballots ----
    if (tid < 256) { const int rr = tid >> 7, t = tid & 127;
                     s_nf[rr][t] = nf[(row0 + rr) * DD + t]; }
    const int mr = tid >> 8;             // row this thread ballots for
    const int jj = tid & 255;
    const int* mrow = mask + (size_t)(row0 + mr) * NN;
    const bool m0 = (mrow[jj]       != 0);
    const bool m1 = (mrow[jj + 256] != 0);
    const ull  bal0 = __ballot(m0);
    const ull  bal1 = __ballot(m1);
    if (lane == 0) {
        s_cnt[mr][(wid & 3)]     = __popcll(bal0);
        s_cnt[mr][(wid & 3) + 4] = __popcll(bal1);
    }
    __syncthreads();

    // ---- S1: scan + phase A (layer-1 GEMVs, 4-way split-k, 2 rows) ----
    if (tid < 2) {
        int a = 0;
        #pragma unroll
        for (int q = 0; q < 8; ++q) { s_off[tid][q] = a; a += s_cnt[tid][q]; }
        s_nact[tid] = a;
    }
    {
        float pS0 = 0.f, pS1 = 0.f, pV0 = 0.f, pV1 = 0.f, pA0 = 0.f, pA1 = 0.f;
        const float4* nq0 = (const float4*)s_nf[0];
        const float4* nq1 = (const float4*)s_nf[1];
        const int kq0 = h * 8;
        #pragma unroll 4
        for (int kk = 0; kk < 8; ++kk) {
            float4 x0 = nq0[kq0 + kk];
            float4 x1 = nq1[kq0 + kk];
            const int k = (kq0 + kk) * 4;
            float w;
            w = Ws1[(k+0)*DD + c]; pS0 = fmaf(x0.x, w, pS0); pS1 = fmaf(x1.x, w, pS1);
            w = Ws1[(k+1)*DD + c]; pS0 = fmaf(x0.y, w, pS0); pS1 = fmaf(x1.y, w, pS1);
            w = Ws1[(k+2)*DD + c]; pS0 = fmaf(x0.z, w, pS0); pS1 = fmaf(x1.z, w, pS1);
            w = Ws1[(k+3)*DD + c]; pS0 = fmaf(x0.w, w, pS0); pS1 = fmaf(x1.w, w, pS1);
            w = Wv1[(k+0)*DD + c]; pV0 = fmaf(x0.x, w, pV0); pV1 = fmaf(x1.x, w, pV1);
            w = Wv1[(k+1)*DD + c]; pV0 = fmaf(x0.y, w, pV0); pV1 = fmaf(x1.y, w, pV1);
            w = Wv1[(k+2)*DD + c]; pV0 = fmaf(x0.z, w, pV0); pV1 = fmaf(x1.z, w, pV1);
            w = Wv1[(k+3)*DD + c]; pV0 = fmaf(x0.w, w, pV0); pV1 = fmaf(x1.w, w, pV1);
            w = Wa1[(k+0)*DD + c]; pA0 = fmaf(x0.x, w, pA0); pA1 = fmaf(x1.x, w, pA1);
            w = Wa1[(k+1)*DD + c]; pA0 = fmaf(x0.y, w, pA0); pA1 = fmaf(x1.y, w, pA1);
            w = Wa1[(k+2)*DD + c]; pA0 = fmaf(x0.z, w, pA0); pA1 = fmaf(x1.z, w, pA1);
            w = Wa1[(k+3)*DD + c]; pA0 = fmaf(x0.w, w, pA0); pA1 = fmaf(x1.w, w, pA1);
        }
        s_part[0][0][h][c] = pS0; s_part[0][1][h][c] = pS1;
        s_part[1][0][h][c] = pV0; s_part[1][1][h][c] = pV1;
        s_part[2][0][h][c] = pA0; s_part[2][1][h][c] = pA1;
    }
    __syncthreads();

    // ---- S2: reduce A -> activations/base; weight quads; compacted writes --
    if (tid < 256) {
        const int rr = tid >> 7, t = tid & 127;
        float vs = s_part[0][rr][0][t] + s_part[0][rr][1][t]
                 + s_part[0][rr][2][t] + s_part[0][rr][3][t] + bs1[t];
        float vv = s_part[1][rr][0][t] + s_part[1][rr][1][t]
                 + s_part[1][rr][2][t] + s_part[1][rr][3][t] + bv1[t];
        float va = s_part[2][rr][0][t] + s_part[2][rr][1][t]
                 + s_part[2][rr][2][t] + s_part[2][rr][3][t] + ba1[t];
        s_hs[rr][t] = silu_f(vs);
        s_hv[rr][t] = silu_f(vv);
        s_bb[rr][t] = -LOG2E * va;
    } else if (tid < 384) {
        const int t = tid - 256;
        float4 w;
        w.x = -LOG2E * Wa1[128 * DD + t];
        w.y = -LOG2E * Wa1[129 * DD + t];
        w.z = -LOG2E * Wa1[130 * DD + t];
        w.w = -Wa2[t];
        s_w4[t] = w;
    }
    {
        const ull lm = (1ull << lane) - 1ull;
        if (m0) s_act[mr][s_off[mr][(wid & 3)]     + __popcll(bal0 & lm)] = (short)jj;
        if (m1) s_act[mr][s_off[mr][(wid & 3) + 4] + __popcll(bal1 & lm)] = (short)(jj + 256);
    }
    __syncthreads();

    // ---- S3: phase B (Ws2) + vf3 partials + attention pass-1 ----
    {
        float p0 = 0.f, p1 = 0.f;
        const float4* h0 = (const float4*)s_hs[0];
        const float4* h1 = (const float4*)s_hs[1];
        const int kq0 = h * 8;
        #pragma unroll 4
        for (int kk = 0; kk < 8; ++kk) {
            float4 x0 = h0[kq0 + kk];
            float4 x1 = h1[kq0 + kk];
            const int k = (kq0 + kk) * 4;
            float w;
            w = Ws2[(k+0)*DD + c]; p0 = fmaf(x0.x, w, p0); p1 = fmaf(x1.x, w, p1);
            w = Ws2[(k+1)*DD + c]; p0 = fmaf(x0.y, w, p0); p1 = fmaf(x1.y, w, p1);
            w = Ws2[(k+2)*DD + c]; p0 = fmaf(x0.z, w, p0); p1 = fmaf(x1.z, w, p1);
            w = Ws2[(k+3)*DD + c]; p0 = fmaf(x0.w, w, p0); p1 = fmaf(x1.w, w, p1);
        }
        s_part[0][0][h][c] = p0; s_part[0][1][h][c] = p1;
    }
    if (tid < 192) {
        const int rr  = tid / 96;
        const int rem = tid % 96;
        const int col = rem >> 5;
        const int kq  = rem & 31;
        float vp = 0.f;
        #pragma unroll
        for (int uu = 0; uu < 4; ++uu) {
            const int k = 4 * kq + uu;
            vp = fmaf(s_hv[rr][k], Wv2[k * DD + col], vp);
        }
        s_vp[tid] = vp;
    }

    const int n0 = __builtin_amdgcn_readfirstlane(s_nact[0]);
    const int n1 = __builtin_amdgcn_readfirstlane(s_nact[1]);
    const float ba2l = ba2p[0] * LOG2E;
    float xiv[2][3];
    #pragma unroll
    for (int rr = 0; rr < 2; ++rr)
        #pragma unroll
        for (int cc = 0; cc < 3; ++cc) xiv[rr][cc] = coords[(row0 + rr) * 3 + cc];
    const float* cb = coords + (size_t)b * NN * 3;

    // wave-uniform round guards
    const bool g00 = (ub      ) < n0, g01 = (ub + 128) < n0,
               g02 = (ub + 256) < n0, g03 = (ub + 384) < n0;
    const bool g10 = (ub      ) < n1, g11 = (ub + 128) < n1,
               g12 = (ub + 256) < n1, g13 = (ub + 384) < n1;

    float f1_00=0,f2_00=0,f3_00=0,a00=0, f1_01=0,f2_01=0,f3_01=0,a01=0;
    float f1_02=0,f2_02=0,f3_02=0,a02=0, f1_03=0,f2_03=0,f3_03=0,a03=0;
    float f1_10=0,f2_10=0,f3_10=0,a10=0, f1_11=0,f2_11=0,f3_11=0,a11=0;
    float f1_12=0,f2_12=0,f3_12=0,a12=0, f1_13=0,f2_13=0,f3_13=0,a13=0;

    if (g00) SETUP(0, u      , n0, f1_00, f2_00, f3_00);
    if (g01) SETUP(0, u + 128, n0, f1_01, f2_01, f3_01);
    if (g02) SETUP(0, u + 256, n0, f1_02, f2_02, f3_02);
    if (g03) SETUP(0, u + 384, n0, f1_03, f2_03, f3_03);
    if (g10) SETUP(1, u      , n1, f1_10, f2_10, f3_10);
    if (g11) SETUP(1, u + 128, n1, f1_11, f2_11, f3_11);
    if (g12) SETUP(1, u + 256, n1, f1_12, f2_12, f3_12);
    if (g13) SETUP(1, u + 384, n1, f1_13, f2_13, f3_13);

    {
        const float4* bb0 = (const float4*)s_bb[0];
        const float4* bb1 = (const float4*)s_bb[1];
        #pragma unroll 2
        for (int tt = 0; tt < 8; ++tt) {
            const int t4 = h * 8 + tt;      // h is wave-uniform (tid>>7)
            float4 W0 = s_w4[4 * t4 + 0];
            float4 W1 = s_w4[4 * t4 + 1];
            float4 W2 = s_w4[4 * t4 + 2];
            float4 W3 = s_w4[4 * t4 + 3];
            float4 bA = bb0[t4];
            float4 bB = bb1[t4];
            if (g00) { UPD4(bA, f1_00, f2_00, f3_00, a00) }
            if (g01) { UPD4(bA, f1_01, f2_01, f3_01, a01) }
            if (g10) { UPD4(bB, f1_10, f2_10, f3_10, a10) }
            if (g11) { UPD4(bB, f1_11, f2_11, f3_11, a11) }
            if (g02) { UPD4(bA, f1_02, f2_02, f3_02, a02) }
            if (g12) { UPD4(bB, f1_12, f2_12, f3_12, a12) }
            if (g03) { UPD4(bA, f1_03, f2_03, f3_03, a03) }
            if (g13) { UPD4(bB, f1_13, f2_13, f3_13, a13) }
        }
    }
    // write all partials (inactive slots hold 0) — q4 == h
    s_lg[0][h][u      ] = a00;
    s_lg[0][h][u + 128] = a01;
    s_lg[0][h][u + 256] = a02;
    s_lg[0][h][u + 384] = a03;
    s_lg[1][h][u      ] = a10;
    s_lg[1][h][u + 128] = a11;
    s_lg[1][h][u + 256] = a12;
    s_lg[1][h][u + 384] = a13;
    __syncthreads();

    // ---- S4: scalar output + logit combine + per-row max ----
    if (tid < 256) {
        const int rr = tid >> 7, t = tid & 127;
        scalar_out[(row0 + rr) * DD + t] =
            s_part[0][rr][0][t] + s_part[0][rr][1][t] +
            s_part[0][rr][2][t] + s_part[0][rr][3][t] + bs2[t];
    }
    const int rw = tid >> 8;             // wave-uniform row for combine
    const int uc = tid & 255;
    const int nw = rw ? n1 : n0;
    const bool vA = uc < nw;
    const bool vB = uc + 256 < nw;
    const float lgA = s_lg[rw][0][uc] + s_lg[rw][1][uc]
                    + s_lg[rw][2][uc] + s_lg[rw][3][uc] + ba2l;
    const float lgB = s_lg[rw][0][uc + 256] + s_lg[rw][1][uc + 256]
                    + s_lg[rw][2][uc + 256] + s_lg[rw][3][uc + 256] + ba2l;
    float mloc = -__builtin_inff();
    if (vA) mloc = lgA;
    if (vB) mloc = fmaxf(mloc, lgB);
    #pragma unroll
    for (int ofs = 32; ofs >= 1; ofs >>= 1) mloc = fmaxf(mloc, __shfl_xor(mloc, ofs));
    if (lane == 0) s_red[rw][wid & 3] = mloc;
    __syncthreads();

    // ---- S5: pass-2 ----
    const float mx = fmaxf(fmaxf(s_red[rw][0], s_red[rw][1]),
                           fmaxf(s_red[rw][2], s_red[rw][3]));
    float es = 0.f, wx = 0.f, wy = 0.f, wz = 0.f;
    if (vA) {
        const int j = ((int)s_act[rw][uc]) & (NN - 1);
        float dx = xiv[rw][0] - cb[j * 3 + 0];
        float dy = xiv[rw][1] - cb[j * 3 + 1];
        float dz = xiv[rw][2] - cb[j * 3 + 2];
        float e  = exp2_hw(lgA - mx);
        es += e; wx = fmaf(e, dx, wx); wy = fmaf(e, dy, wy); wz = fmaf(e, dz, wz);
    }
    if (vB) {
        const int j = ((int)s_act[rw][uc + 256]) & (NN - 1);
        float dx = xiv[rw][0] - cb[j * 3 + 0];
        float dy = xiv[rw][1] - cb[j * 3 + 1];
        float dz = xiv[rw][2] - cb[j * 3 + 2];
        float e  = exp2_hw(lgB - mx);
        es += e; wx = fmaf(e, dx, wx); wy = fmaf(e, dy, wy); wz = fmaf(e, dz, wz);
    }
    #pragma unroll
    for (int ofs = 32; ofs >= 1; ofs >>= 1) {
        es += __shfl_xor(es, ofs);
        wx += __shfl_xor(wx, ofs);
        wy += __shfl_xor(wy, ofs);
        wz += __shfl_xor(wz, ofs);
    }
    if (lane == 0) {
        s_red2[rw][wid & 3][0] = es; s_red2[rw][wid & 3][1] = wx;
        s_red2[rw][wid & 3][2] = wy; s_red2[rw][wid & 3][3] = wz;
    }
    __syncthreads();

    // ---- S6: final vector outputs ----
    if (tid < 6) {
        const int rr = tid / 3, cc = tid % 3;
        float tot = s_red2[rr][0][0] + s_red2[rr][1][0]
                  + s_red2[rr][2][0] + s_red2[rr][3][0];
        float num = s_red2[rr][0][1+cc] + s_red2[rr][1][1+cc]
                  + s_red2[rr][2][1+cc] + s_red2[rr][3][1+cc];
        float vf = bv2[cc];
        const float* pp = &s_vp[rr * 96 + cc * 32];
        #pragma unroll 8
        for (int q = 0; q < 32; ++q) vf += pp[q];
        vec_out[(row0 + rr) * 3 + cc] = (num / tot) * vf;
    }
}

extern "C" void kernel_launch(void* const* d_in, const int* in_sizes, int n_in,
                              void* d_out, int out_size, void* d_ws, size_t ws_size,
                              hipStream_t stream) {
    const float* nf     = (const float*)d_in[0];
    const float* coords = (const float*)d_in[1];
    const int*   mask   = (const int*)  d_in[2];
    const float* Ws1 = (const float*)d_in[3];  const float* bs1 = (const float*)d_in[4];
    const float* Ws2 = (const float*)d_in[5];  const float* bs2 = (const float*)d_in[6];
    const float* Wv1 = (const float*)d_in[7];  const float* bv1 = (const float*)d_in[8];
    const float* Wv2 = (const float*)d_in[9];  const float* bv2 = (const float*)d_in[10];
    const float* Wa1 = (const float*)d_in[11]; const float* ba1 = (const float*)d_in[12];
    const float* Wa2 = (const float*)d_in[13]; const float* ba2 = (const float*)d_in[14];

    float* scalar_out = (float*)d_out;                   // [NB*NN*DD]
    float* vec_out    = (float*)d_out + NB * NN * DD;    // [NB*NN*3]

    hipLaunchKernelGGL(k_all, dim3(NB * NN / 2), dim3(512), 0, stream,
                       nf, coords, mask,
                       Ws1, bs1, Ws2, bs2, Wv1, bv1, Wv2, bv2,
                       Wa1, ba1, Wa2, ba2,
                       scalar_out, vec_out);
}

// Round 10
// 26.427 us; speedup vs baseline: 1.0992x; 1.0070x over previous
//
#include <hip/hip_runtime.h>
#include <math.h>

#define NB 2
#define NN 512
#define DD 128
#define LOG2E 1.4426950408889634f

typedef unsigned long long ull;

__device__ __forceinline__ float exp2_hw(float x) {
    float r; asm("v_exp_f32 %0, %1" : "=v"(r) : "v"(x)); return r;
}
__device__ __forceinline__ float silu_f(float x) {
    float e = exp2_hw(-LOG2E * x);
    return x * __builtin_amdgcn_rcpf(1.0f + e);
}

// pre = bb + f1*Wq.x + f2*Wq.y + f3*Wq.z (log2-scaled), acc += pre*Wq.w*sigmoid
#define UPD1(Wq, BBC, F1, F2, F3, ACC)                                         \
    { float pre = fmaf(F3, Wq.z, fmaf(F2, Wq.y, fmaf(F1, Wq.x, BBC)));         \
      float e   = exp2_hw(pre);                                                \
      float rc  = __builtin_amdgcn_rcpf(1.0f + e);                             \
      ACC = fmaf(pre * Wq.w, rc, ACC); }

#define UPD4(BB, F1, F2, F3, ACC)                                              \
    UPD1(W0, BB.x, F1, F2, F3, ACC) UPD1(W1, BB.y, F1, F2, F3, ACC)            \
    UPD1(W2, BB.z, F1, F2, F3, ACC) UPD1(W3, BB.w, F1, F2, F3, ACC)

#define SETUP(rr, A, NACT, F1, F2, F3)                                         \
    { int a_ = (A);                                                            \
      int j_ = ((int)s_act[rr][(a_ < (NACT)) ? a_ : 0]) & (NN - 1);            \
      float dx_ = xiv[rr][0] - cb[j_ * 3 + 0];                                 \
      float dy_ = xiv[rr][1] - cb[j_ * 3 + 1];                                 \
      float dz_ = xiv[rr][2] - cb[j_ * 3 + 2];                                 \
      float d_  = sqrtf(fmaf(dx_, dx_, fmaf(dy_, dy_, dz_ * dz_)));            \
      F1 = d_;                                                                 \
      float x_  = d_ + 1e-6f;                                                  \
      float rc_ = __builtin_amdgcn_rcpf(x_);                                   \
      F2 = rc_ * fmaf(-x_, rc_, 2.0f);                                         \
      F3 = exp2_hw(-LOG2E * d_); }

// ---------------------------------------------------------------------------
// 512 blocks x 512 threads, 2 rows per block (R9 structure), with the softmax
// reduction merged into ONE phase: per-wave max + per-wave partial sums
// (register shuffles only), then a single barrier and a 4-way rescaled
// combine (2^(m_w - M) factors). ba2 dropped (softmax shift-invariant).
// Deterministic compaction (ballot+scan, no atomics).
// ---------------------------------------------------------------------------
__global__ __launch_bounds__(512) void k_all(
    const float* __restrict__ nf,
    const float* __restrict__ coords,
    const int*   __restrict__ mask,
    const float* __restrict__ Ws1, const float* __restrict__ bs1,
    const float* __restrict__ Ws2, const float* __restrict__ bs2,
    const float* __restrict__ Wv1, const float* __restrict__ bv1,
    const float* __restrict__ Wv2, const float* __restrict__ bv2,
    const float* __restrict__ Wa1, const float* __restrict__ ba1,
    const float* __restrict__ Wa2, const float* __restrict__ ba2p,
    float* __restrict__ scalar_out,
    float* __restrict__ vec_out)
{
    __shared__ __align__(16) float  s_nf[2][DD];
    __shared__ __align__(16) float  s_hs[2][DD];
    __shared__ __align__(16) float  s_hv[2][DD];
    __shared__ __align__(16) float  s_bb[2][DD];     // -l2e*base per row
    __shared__ __align__(16) float4 s_w4[DD];        // (-l2e*w0,-l2e*w1,-l2e*w2,-Wa2)
    __shared__ float  s_part[3][2][4][DD];           // [mat][row][kquarter][col]
    __shared__ float  s_lg[2][4][NN];                // [row][q4][a] partial logits
    __shared__ short  s_act[2][NN];
    __shared__ float  s_vp[192];
    __shared__ int    s_cnt[2][8], s_off[2][8], s_nact[2];
    __shared__ float  s_red2[2][4][5];               // es,wx,wy,wz,m_w per wave

    const int row0 = blockIdx.x * 2;
    const int b    = row0 >> 9;
    const int tid  = threadIdx.x;
    const int lane = tid & 63;
    const int wid  = tid >> 6;           // 0..7
    const int c    = tid & 127;
    const int h    = tid >> 7;           // 0..3 (k-quarter / t4-quarter)
    const int u    = tid & 127;
    const int ub   = tid & 64;           // wave-uniform u base

    // ---- S0: load nf + mask ballots ----
    if (tid < 256) { const int rr = tid >> 7, t = tid & 127;
                     s_nf[rr][t] = nf[(row0 + rr) * DD + t]; }
    const int mr = tid >> 8;             // row this thread ballots for
    const int jj = tid & 255;
    const int* mrow = mask + (size_t)(row0 + mr) * NN;
    const bool m0 = (mrow[jj]       != 0);
    const bool m1 = (mrow[jj + 256] != 0);
    const ull  bal0 = __ballot(m0);
    const ull  bal1 = __ballot(m1);
    if (lane == 0) {
        s_cnt[mr][(wid & 3)]     = __popcll(bal0);
        s_cnt[mr][(wid & 3) + 4] = __popcll(bal1);
    }
    __syncthreads();

    // ---- S1: scan + phase A (layer-1 GEMVs, 4-way split-k, 2 rows) ----
    if (tid < 2) {
        int a = 0;
        #pragma unroll
        for (int q = 0; q < 8; ++q) { s_off[tid][q] = a; a += s_cnt[tid][q]; }
        s_nact[tid] = a;
    }
    {
        float pS0 = 0.f, pS1 = 0.f, pV0 = 0.f, pV1 = 0.f, pA0 = 0.f, pA1 = 0.f;
        const float4* nq0 = (const float4*)s_nf[0];
        const float4* nq1 = (const float4*)s_nf[1];
        const int kq0 = h * 8;
        #pragma unroll 4
        for (int kk = 0; kk < 8; ++kk) {
            float4 x0 = nq0[kq0 + kk];
            float4 x1 = nq1[kq0 + kk];
            const int k = (kq0 + kk) * 4;
            float w;
            w = Ws1[(k+0)*DD + c]; pS0 = fmaf(x0.x, w, pS0); pS1 = fmaf(x1.x, w, pS1);
            w = Ws1[(k+1)*DD + c]; pS0 = fmaf(x0.y, w, pS0); pS1 = fmaf(x1.y, w, pS1);
            w = Ws1[(k+2)*DD + c]; pS0 = fmaf(x0.z, w, pS0); pS1 = fmaf(x1.z, w, pS1);
            w = Ws1[(k+3)*DD + c]; pS0 = fmaf(x0.w, w, pS0); pS1 = fmaf(x1.w, w, pS1);
            w = Wv1[(k+0)*DD + c]; pV0 = fmaf(x0.x, w, pV0); pV1 = fmaf(x1.x, w, pV1);
            w = Wv1[(k+1)*DD + c]; pV0 = fmaf(x0.y, w, pV0); pV1 = fmaf(x1.y, w, pV1);
            w = Wv1[(k+2)*DD + c]; pV0 = fmaf(x0.z, w, pV0); pV1 = fmaf(x1.z, w, pV1);
            w = Wv1[(k+3)*DD + c]; pV0 = fmaf(x0.w, w, pV0); pV1 = fmaf(x1.w, w, pV1);
            w = Wa1[(k+0)*DD + c]; pA0 = fmaf(x0.x, w, pA0); pA1 = fmaf(x1.x, w, pA1);
            w = Wa1[(k+1)*DD + c]; pA0 = fmaf(x0.y, w, pA0); pA1 = fmaf(x1.y, w, pA1);
            w = Wa1[(k+2)*DD + c]; pA0 = fmaf(x0.z, w, pA0); pA1 = fmaf(x1.z, w, pA1);
            w = Wa1[(k+3)*DD + c]; pA0 = fmaf(x0.w, w, pA0); pA1 = fmaf(x1.w, w, pA1);
        }
        s_part[0][0][h][c] = pS0; s_part[0][1][h][c] = pS1;
        s_part[1][0][h][c] = pV0; s_part[1][1][h][c] = pV1;
        s_part[2][0][h][c] = pA0; s_part[2][1][h][c] = pA1;
    }
    __syncthreads();

    // ---- S2: reduce A -> activations/base; weight quads; compacted writes --
    if (tid < 256) {
        const int rr = tid >> 7, t = tid & 127;
        float vs = s_part[0][rr][0][t] + s_part[0][rr][1][t]
                 + s_part[0][rr][2][t] + s_part[0][rr][3][t] + bs1[t];
        float vv = s_part[1][rr][0][t] + s_part[1][rr][1][t]
                 + s_part[1][rr][2][t] + s_part[1][rr][3][t] + bv1[t];
        float va = s_part[2][rr][0][t] + s_part[2][rr][1][t]
                 + s_part[2][rr][2][t] + s_part[2][rr][3][t] + ba1[t];
        s_hs[rr][t] = silu_f(vs);
        s_hv[rr][t] = silu_f(vv);
        s_bb[rr][t] = -LOG2E * va;
    } else if (tid < 384) {
        const int t = tid - 256;
        float4 w;
        w.x = -LOG2E * Wa1[128 * DD + t];
        w.y = -LOG2E * Wa1[129 * DD + t];
        w.z = -LOG2E * Wa1[130 * DD + t];
        w.w = -Wa2[t];
        s_w4[t] = w;
    }
    {
        const ull lm = (1ull << lane) - 1ull;
        if (m0) s_act[mr][s_off[mr][(wid & 3)]     + __popcll(bal0 & lm)] = (short)jj;
        if (m1) s_act[mr][s_off[mr][(wid & 3) + 4] + __popcll(bal1 & lm)] = (short)(jj + 256);
    }
    __syncthreads();

    // ---- S3: phase B (Ws2) + vf3 partials + attention pass-1 ----
    {
        float p0 = 0.f, p1 = 0.f;
        const float4* h0 = (const float4*)s_hs[0];
        const float4* h1 = (const float4*)s_hs[1];
        const int kq0 = h * 8;
        #pragma unroll 4
        for (int kk = 0; kk < 8; ++kk) {
            float4 x0 = h0[kq0 + kk];
            float4 x1 = h1[kq0 + kk];
            const int k = (kq0 + kk) * 4;
            float w;
            w = Ws2[(k+0)*DD + c]; p0 = fmaf(x0.x, w, p0); p1 = fmaf(x1.x, w, p1);
            w = Ws2[(k+1)*DD + c]; p0 = fmaf(x0.y, w, p0); p1 = fmaf(x1.y, w, p1);
            w = Ws2[(k+2)*DD + c]; p0 = fmaf(x0.z, w, p0); p1 = fmaf(x1.z, w, p1);
            w = Ws2[(k+3)*DD + c]; p0 = fmaf(x0.w, w, p0); p1 = fmaf(x1.w, w, p1);
        }
        s_part[0][0][h][c] = p0; s_part[0][1][h][c] = p1;
    }
    if (tid < 192) {
        const int rr  = tid / 96;
        const int rem = tid % 96;
        const int col = rem >> 5;
        const int kq  = rem & 31;
        float vp = 0.f;
        #pragma unroll
        for (int uu = 0; uu < 4; ++uu) {
            const int k = 4 * kq + uu;
            vp = fmaf(s_hv[rr][k], Wv2[k * DD + col], vp);
        }
        s_vp[tid] = vp;
    }

    const int n0 = __builtin_amdgcn_readfirstlane(s_nact[0]);
    const int n1 = __builtin_amdgcn_readfirstlane(s_nact[1]);
    float xiv[2][3];
    #pragma unroll
    for (int rr = 0; rr < 2; ++rr)
        #pragma unroll
        for (int cc = 0; cc < 3; ++cc) xiv[rr][cc] = coords[(row0 + rr) * 3 + cc];
    const float* cb = coords + (size_t)b * NN * 3;

    // wave-uniform round guards
    const bool g00 = (ub      ) < n0, g01 = (ub + 128) < n0,
               g02 = (ub + 256) < n0, g03 = (ub + 384) < n0;
    const bool g10 = (ub      ) < n1, g11 = (ub + 128) < n1,
               g12 = (ub + 256) < n1, g13 = (ub + 384) < n1;

    float f1_00=0,f2_00=0,f3_00=0,a00=0, f1_01=0,f2_01=0,f3_01=0,a01=0;
    float f1_02=0,f2_02=0,f3_02=0,a02=0, f1_03=0,f2_03=0,f3_03=0,a03=0;
    float f1_10=0,f2_10=0,f3_10=0,a10=0, f1_11=0,f2_11=0,f3_11=0,a11=0;
    float f1_12=0,f2_12=0,f3_12=0,a12=0, f1_13=0,f2_13=0,f3_13=0,a13=0;

    if (g00) SETUP(0, u      , n0, f1_00, f2_00, f3_00);
    if (g01) SETUP(0, u + 128, n0, f1_01, f2_01, f3_01);
    if (g02) SETUP(0, u + 256, n0, f1_02, f2_02, f3_02);
    if (g03) SETUP(0, u + 384, n0, f1_03, f2_03, f3_03);
    if (g10) SETUP(1, u      , n1, f1_10, f2_10, f3_10);
    if (g11) SETUP(1, u + 128, n1, f1_11, f2_11, f3_11);
    if (g12) SETUP(1, u + 256, n1, f1_12, f2_12, f3_12);
    if (g13) SETUP(1, u + 384, n1, f1_13, f2_13, f3_13);

    {
        const float4* bb0 = (const float4*)s_bb[0];
        const float4* bb1 = (const float4*)s_bb[1];
        #pragma unroll 2
        for (int tt = 0; tt < 8; ++tt) {
            const int t4 = h * 8 + tt;      // h is wave-uniform (tid>>7)
            float4 W0 = s_w4[4 * t4 + 0];
            float4 W1 = s_w4[4 * t4 + 1];
            float4 W2 = s_w4[4 * t4 + 2];
            float4 W3 = s_w4[4 * t4 + 3];
            float4 bA = bb0[t4];
            float4 bB = bb1[t4];
            if (g00) { UPD4(bA, f1_00, f2_00, f3_00, a00) }
            if (g01) { UPD4(bA, f1_01, f2_01, f3_01, a01) }
            if (g10) { UPD4(bB, f1_10, f2_10, f3_10, a10) }
            if (g11) { UPD4(bB, f1_11, f2_11, f3_11, a11) }
            if (g02) { UPD4(bA, f1_02, f2_02, f3_02, a02) }
            if (g12) { UPD4(bB, f1_12, f2_12, f3_12, a12) }
            if (g03) { UPD4(bA, f1_03, f2_03, f3_03, a03) }
            if (g13) { UPD4(bB, f1_13, f2_13, f3_13, a13) }
        }
    }
    // write all partials (inactive slots hold 0) — q4 == h
    s_lg[0][h][u      ] = a00;
    s_lg[0][h][u + 128] = a01;
    s_lg[0][h][u + 256] = a02;
    s_lg[0][h][u + 384] = a03;
    s_lg[1][h][u      ] = a10;
    s_lg[1][h][u + 128] = a11;
    s_lg[1][h][u + 256] = a12;
    s_lg[1][h][u + 384] = a13;
    __syncthreads();

    // ---- S4: scalar output + MERGED softmax (per-wave max + partials,
    //         shuffles only, ONE barrier, rescaled 4-way combine) ----
    if (tid < 256) {
        const int rr = tid >> 7, t = tid & 127;
        scalar_out[(row0 + rr) * DD + t] =
            s_part[0][rr][0][t] + s_part[0][rr][1][t] +
            s_part[0][rr][2][t] + s_part[0][rr][3][t] + bs2[t];
    }
    const int rw = tid >> 8;             // wave-uniform row for combine
    const int uc = tid & 255;
    const int nw = rw ? n1 : n0;
    const bool vA = uc < nw;
    const bool vB = uc + 256 < nw;
    // ba2 dropped: softmax is shift-invariant.
    const float lgA = s_lg[rw][0][uc] + s_lg[rw][1][uc]
                    + s_lg[rw][2][uc] + s_lg[rw][3][uc];
    const float lgB = s_lg[rw][0][uc + 256] + s_lg[rw][1][uc + 256]
                    + s_lg[rw][2][uc + 256] + s_lg[rw][3][uc + 256];
    float mloc = -__builtin_inff();
    if (vA) mloc = lgA;
    if (vB) mloc = fmaxf(mloc, lgB);
    #pragma unroll
    for (int ofs = 32; ofs >= 1; ofs >>= 1) mloc = fmaxf(mloc, __shfl_xor(mloc, ofs));
    // mloc is now wave-uniform m_w
    float es = 0.f, wx = 0.f, wy = 0.f, wz = 0.f;
    if (vA) {
        const int j = ((int)s_act[rw][uc]) & (NN - 1);
        float dx = xiv[rw][0] - cb[j * 3 + 0];
        float dy = xiv[rw][1] - cb[j * 3 + 1];
        float dz = xiv[rw][2] - cb[j * 3 + 2];
        float e  = exp2_hw(lgA - mloc);
        es += e; wx = fmaf(e, dx, wx); wy = fmaf(e, dy, wy); wz = fmaf(e, dz, wz);
    }
    if (vB) {
        const int j = ((int)s_act[rw][uc + 256]) & (NN - 1);
        float dx = xiv[rw][0] - cb[j * 3 + 0];
        float dy = xiv[rw][1] - cb[j * 3 + 1];
        float dz = xiv[rw][2] - cb[j * 3 + 2];
        float e  = exp2_hw(lgB - mloc);
        es += e; wx = fmaf(e, dx, wx); wy = fmaf(e, dy, wy); wz = fmaf(e, dz, wz);
    }
    #pragma unroll
    for (int ofs = 32; ofs >= 1; ofs >>= 1) {
        es += __shfl_xor(es, ofs);
        wx += __shfl_xor(wx, ofs);
        wy += __shfl_xor(wy, ofs);
        wz += __shfl_xor(wz, ofs);
    }
    if (lane == 0) {
        s_red2[rw][wid & 3][0] = es; s_red2[rw][wid & 3][1] = wx;
        s_red2[rw][wid & 3][2] = wy; s_red2[rw][wid & 3][3] = wz;
        s_red2[rw][wid & 3][4] = mloc;
    }
    __syncthreads();

    // ---- S5: final vector outputs (rescaled combine of 4 wave partials) ----
    if (tid < 6) {
        const int rr = tid / 3, cc = tid % 3;
        const float mA = s_red2[rr][0][4], mB = s_red2[rr][1][4];
        const float mC = s_red2[rr][2][4], mD = s_red2[rr][3][4];
        const float M  = fmaxf(fmaxf(mA, mB), fmaxf(mC, mD));
        const float sA = exp2_hw(mA - M), sB = exp2_hw(mB - M);
        const float sC = exp2_hw(mC - M), sD = exp2_hw(mD - M);
        float tot = sA * s_red2[rr][0][0] + sB * s_red2[rr][1][0]
                  + sC * s_red2[rr][2][0] + sD * s_red2[rr][3][0];
        float num = sA * s_red2[rr][0][1+cc] + sB * s_red2[rr][1][1+cc]
                  + sC * s_red2[rr][2][1+cc] + sD * s_red2[rr][3][1+cc];
        float vf = bv2[cc];
        const float* pp = &s_vp[rr * 96 + cc * 32];
        #pragma unroll 8
        for (int q = 0; q < 32; ++q) vf += pp[q];
        vec_out[(row0 + rr) * 3 + cc] = (num / tot) * vf;
    }
}

extern "C" void kernel_launch(void* const* d_in, const int* in_sizes, int n_in,
                              void* d_out, int out_size, void* d_ws, size_t ws_size,
                              hipStream_t stream) {
    const float* nf     = (const float*)d_in[0];
    const float* coords = (const float*)d_in[1];
    const int*   mask   = (const int*)  d_in[2];
    const float* Ws1 = (const float*)d_in[3];  const float* bs1 = (const float*)d_in[4];
    const float* Ws2 = (const float*)d_in[5];  const float* bs2 = (const float*)d_in[6];
    const float* Wv1 = (const float*)d_in[7];  const float* bv1 = (const float*)d_in[8];
    const float* Wv2 = (const float*)d_in[9];  const float* bv2 = (const float*)d_in[10];
    const float* Wa1 = (const float*)d_in[11]; const float* ba1 = (const float*)d_in[12];
    const float* Wa2 = (const float*)d_in[13]; const float* ba2 = (const float*)d_in[14];

    float* scalar_out = (float*)d_out;                   // [NB*NN*DD]
    float* vec_out    = (float*)d_out + NB * NN * DD;    // [NB*NN*3]

    hipLaunchKernelGGL(k_all, dim3(NB * NN / 2), dim3(512), 0, stream,
                       nf, coords, mask,
                       Ws1, bs1, Ws2, bs2, Wv1, bv1, Wv2, bv2,
                       Wa1, ba1, Wa2, ba2,
                       scalar_out, vec_out);
}